// Round 1
// baseline (1074.758 us; speedup 1.0000x reference)
//
#include <hip/hip_runtime.h>
#include <hip/hip_bf16.h>
#include <math.h>

// Node classifier: KProp(K=2, gcn_norm) -> SAGEConv(64->64)+selu -> SAGEConv(64->40) -> softmax
// N=100000, E=1600000, D=H=64, C=40. All fp32.
//
// Strategy: build CSR (by dst) once per call, then 4 gather-based propagation
// passes (no atomics in the hot loops), fused GEMM+selu and GEMM+softmax.

#define WAVE 64

// ---------------- small utility kernels ----------------

__global__ void zero_int_kernel(int* __restrict__ p, int n) {
    int i = blockIdx.x * blockDim.x + threadIdx.x;
    if (i < n) p[i] = 0;
}

__global__ void deg_count_kernel(const int* __restrict__ dst, int* __restrict__ deg, int e) {
    int i = blockIdx.x * blockDim.x + threadIdx.x;
    if (i < e) atomicAdd(&deg[dst[i]], 1);
}

// Per-block inclusive scan (block = 1024), writes inclusive partials + block sums.
__global__ __launch_bounds__(1024) void scan1_kernel(const int* __restrict__ deg,
                                                     int* __restrict__ incl,
                                                     int* __restrict__ bsum, int n) {
    __shared__ int tmp[1024];
    int t = threadIdx.x;
    int gi = blockIdx.x * 1024 + t;
    int v = (gi < n) ? deg[gi] : 0;
    tmp[t] = v;
    __syncthreads();
    for (int off = 1; off < 1024; off <<= 1) {
        int u = (t >= off) ? tmp[t - off] : 0;
        __syncthreads();
        tmp[t] += u;
        __syncthreads();
    }
    if (gi < n) incl[gi] = tmp[t];
    if (t == 1023) bsum[blockIdx.x] = tmp[1023];
}

// Exclusive scan of block sums (single block, up to 1024 entries).
__global__ __launch_bounds__(1024) void scan2_kernel(int* __restrict__ bsum, int nb) {
    __shared__ int tmp[1024];
    int t = threadIdx.x;
    int v = (t < nb) ? bsum[t] : 0;
    tmp[t] = v;
    __syncthreads();
    for (int off = 1; off < 1024; off <<= 1) {
        int u = (t >= off) ? tmp[t - off] : 0;
        __syncthreads();
        tmp[t] += u;
        __syncthreads();
    }
    if (t < nb) bsum[t] = tmp[t] - v;   // exclusive
}

// Finalize: row_ptr exclusive, cursor copy, dis = deg>0 ? rsqrt(deg) : 0, cnt_inv = 1/max(deg,1)
__global__ void scan3_kernel(const int* __restrict__ deg, int* __restrict__ row_ptr,
                             const int* __restrict__ bsum, int* __restrict__ cursor,
                             float* __restrict__ dis, float* __restrict__ cnt_inv,
                             int n, int e) {
    int i = blockIdx.x * blockDim.x + threadIdx.x;
    if (i >= n) return;
    int d = deg[i];
    int ex = row_ptr[i] - d + bsum[i >> 10];   // inclusive -> exclusive + block offset
    row_ptr[i] = ex;
    cursor[i] = ex;
    float fd = (float)d;
    dis[i] = (d > 0) ? rsqrtf(fd) : 0.0f;
    cnt_inv[i] = 1.0f / fmaxf(fd, 1.0f);
    if (i == 0) row_ptr[n] = e;
}

__global__ void csr_fill_kernel(const int* __restrict__ src, const int* __restrict__ dst,
                                int* __restrict__ cursor, int* __restrict__ csr, int e) {
    int i = blockIdx.x * blockDim.x + threadIdx.x;
    if (i < e) {
        int p = atomicAdd(&cursor[dst[i]], 1);
        csr[p] = src[i];
    }
}

// ---------------- propagation (gather) ----------------
// One wave per node; lane = feature. out[n][lane] = nscale[n] * sum_e w_e * in[src_e][lane]
// USE_W: w_e = dis[src_e] (KProp).  !USE_W: w_e = 1 (mean-aggr numerator).
template <bool USE_W>
__global__ __launch_bounds__(256) void prop_kernel(const float* __restrict__ in,
                                                   float* __restrict__ out,
                                                   const int* __restrict__ row_ptr,
                                                   const int* __restrict__ csr_src,
                                                   const float* __restrict__ dis,
                                                   const float* __restrict__ nscale,
                                                   int n) {
    int wid = threadIdx.x >> 6;
    int lane = threadIdx.x & 63;
    int node = blockIdx.x * 4 + wid;
    if (node >= n) return;
    int beg = row_ptr[node];
    int end = row_ptr[node + 1];
    float acc = 0.0f;
    for (int i0 = beg; i0 < end; i0 += WAVE) {
        int rem = end - i0;
        int cnt = rem < WAVE ? rem : WAVE;
        int s = 0;
        float w = 0.0f;
        if (lane < cnt) {
            s = csr_src[i0 + lane];
            if (USE_W) w = dis[s];
        }
        for (int j = 0; j < cnt; ++j) {
            int sj = __shfl(s, j);
            float v = in[sj * 64 + lane];
            if (USE_W) {
                float wj = __shfl(w, j);
                acc += wj * v;
            } else {
                acc += v;
            }
        }
    }
    out[node * 64 + lane] = acc * nscale[node];
}

// ---------------- fused dense layers ----------------
// h1 = selu(agg @ Wl + h @ Wr + b), all 64-dim. One wave per node, lane = out col.
__global__ __launch_bounds__(256) void gemm1_selu_kernel(const float* __restrict__ agg,
                                                         const float* __restrict__ h,
                                                         const float* __restrict__ Wl,
                                                         const float* __restrict__ Wr,
                                                         const float* __restrict__ b,
                                                         float* __restrict__ out, int n) {
    __shared__ float sWl[64 * 64];
    __shared__ float sWr[64 * 64];
    __shared__ float sb[64];
    for (int i = threadIdx.x; i < 64 * 64; i += 256) {
        sWl[i] = Wl[i];
        sWr[i] = Wr[i];
    }
    if (threadIdx.x < 64) sb[threadIdx.x] = b[threadIdx.x];
    __syncthreads();
    int wid = threadIdx.x >> 6;
    int lane = threadIdx.x & 63;
    int node = blockIdx.x * 4 + wid;
    if (node >= n) return;
    float a = agg[node * 64 + lane];
    float hh = h[node * 64 + lane];
    float acc = sb[lane];
    for (int k = 0; k < 64; ++k) {
        float ak = __shfl(a, k);
        float hk = __shfl(hh, k);
        acc += ak * sWl[k * 64 + lane] + hk * sWr[k * 64 + lane];
    }
    const float scale = 1.0507009873554805f;
    const float alpha = 1.6732632423543772f;
    acc = scale * (acc > 0.0f ? acc : alpha * expm1f(acc));
    out[node * 64 + lane] = acc;
}

// out = softmax(agg @ Wl2 + h1 @ Wr2 + b2). Wl2/Wr2 are (64,40) row-major. One wave per node.
__global__ __launch_bounds__(256) void gemm2_softmax_kernel(const float* __restrict__ agg,
                                                            const float* __restrict__ h1,
                                                            const float* __restrict__ Wl,
                                                            const float* __restrict__ Wr,
                                                            const float* __restrict__ b,
                                                            float* __restrict__ out, int n) {
    __shared__ float sWl[64 * 40];
    __shared__ float sWr[64 * 40];
    __shared__ float sb[40];
    for (int i = threadIdx.x; i < 64 * 40; i += 256) {
        sWl[i] = Wl[i];
        sWr[i] = Wr[i];
    }
    if (threadIdx.x < 40) sb[threadIdx.x] = b[threadIdx.x];
    __syncthreads();
    int wid = threadIdx.x >> 6;
    int lane = threadIdx.x & 63;
    int node = blockIdx.x * 4 + wid;
    if (node >= n) return;
    float a = agg[node * 64 + lane];
    float hh = h1[node * 64 + lane];
    float acc = (lane < 40) ? sb[lane] : 0.0f;
    for (int k = 0; k < 64; ++k) {
        float ak = __shfl(a, k);
        float hk = __shfl(hh, k);
        if (lane < 40) acc += ak * sWl[k * 40 + lane] + hk * sWr[k * 40 + lane];
    }
    float x = (lane < 40) ? acc : -INFINITY;
    float m = x;
    for (int off = 32; off; off >>= 1) m = fmaxf(m, __shfl_xor(m, off));
    float e = (lane < 40) ? __expf(x - m) : 0.0f;
    float ssum = e;
    for (int off = 32; off; off >>= 1) ssum += __shfl_xor(ssum, off);
    if (lane < 40) out[node * 40 + lane] = e / ssum;
}

// ---------------- launch ----------------

extern "C" void kernel_launch(void* const* d_in, const int* in_sizes, int n_in,
                              void* d_out, int out_size, void* d_ws, size_t ws_size,
                              hipStream_t stream) {
    const float* x   = (const float*)d_in[0];
    const float* Wl1 = (const float*)d_in[1];
    const float* Wr1 = (const float*)d_in[2];
    const float* b1  = (const float*)d_in[3];
    const float* Wl2 = (const float*)d_in[4];
    const float* Wr2 = (const float*)d_in[5];
    const float* b2  = (const float*)d_in[6];
    const int* edge_src = (const int*)d_in[7];
    const int* edge_dst = (const int*)d_in[8];
    float* out = (float*)d_out;

    const int N = in_sizes[0] / 64;
    const int E = in_sizes[7];

    // workspace carve-up (256B aligned)
    size_t off = 0;
    auto carve = [&](size_t bytes) -> void* {
        void* p = (char*)d_ws + off;
        off = (off + bytes + 255) & ~(size_t)255;
        return p;
    };
    int*   deg     = (int*)carve((size_t)N * 4);
    int*   row_ptr = (int*)carve((size_t)(N + 1) * 4);
    int*   cursor  = (int*)carve((size_t)N * 4);
    int*   bsum    = (int*)carve(1024 * 4);
    float* dis     = (float*)carve((size_t)N * 4);
    float* cnt_inv = (float*)carve((size_t)N * 4);
    int*   csr_src = (int*)carve((size_t)E * 4);
    float* bufA    = (float*)carve((size_t)N * 64 * 4);
    float* bufB    = (float*)carve((size_t)N * 64 * 4);
    float* bufC    = (float*)carve((size_t)N * 64 * 4);
    (void)ws_size;

    const int nb_n256 = (N + 255) / 256;
    const int nb_e256 = (E + 255) / 256;
    const int nb_scan = (N + 1023) / 1024;
    const int nb_node = (N + 3) / 4;   // 4 waves (nodes) per 256-thread block

    // 1) degree
    zero_int_kernel<<<nb_n256, 256, 0, stream>>>(deg, N);
    deg_count_kernel<<<nb_e256, 256, 0, stream>>>(edge_dst, deg, E);
    // 2) CSR build
    scan1_kernel<<<nb_scan, 1024, 0, stream>>>(deg, row_ptr, bsum, N);
    scan2_kernel<<<1, 1024, 0, stream>>>(bsum, nb_scan);
    scan3_kernel<<<nb_n256, 256, 0, stream>>>(deg, row_ptr, bsum, cursor, dis, cnt_inv, N, E);
    csr_fill_kernel<<<nb_e256, 256, 0, stream>>>(edge_src, edge_dst, cursor, csr_src, E);
    // 3) KProp x2: h = D^-1/2 A D^-1/2 h
    prop_kernel<true><<<nb_node, 256, 0, stream>>>(x,    bufA, row_ptr, csr_src, dis, dis, N);
    prop_kernel<true><<<nb_node, 256, 0, stream>>>(bufA, bufB, row_ptr, csr_src, dis, dis, N);
    // 4) SAGE1: agg1 = mean-neighbors(h) -> bufA ; h1 = selu(agg1@Wl1 + h@Wr1 + b1) -> bufC
    prop_kernel<false><<<nb_node, 256, 0, stream>>>(bufB, bufA, row_ptr, csr_src, dis, cnt_inv, N);
    gemm1_selu_kernel<<<nb_node, 256, 0, stream>>>(bufA, bufB, Wl1, Wr1, b1, bufC, N);
    // 5) SAGE2: agg2 = mean-neighbors(h1) -> bufA ; out = softmax(agg2@Wl2 + h1@Wr2 + b2)
    prop_kernel<false><<<nb_node, 256, 0, stream>>>(bufC, bufA, row_ptr, csr_src, dis, cnt_inv, N);
    gemm2_softmax_kernel<<<nb_node, 256, 0, stream>>>(bufA, bufC, Wl2, Wr2, b2, out, N);
}

// Round 2
// 619.875 us; speedup vs baseline: 1.7338x; 1.7338x over previous
//
#include <hip/hip_runtime.h>
#include <hip/hip_bf16.h>
#include <math.h>

// Node classifier: KProp(K=2, gcn_norm) -> SAGEConv(64->64)+selu -> SAGEConv(64->40) -> softmax
// N=100000, E=1600000, D=H=64, C=40. All fp32.
//
// R1 structure:
//   CSR build (by dst), then using linearity of mean-aggregation:
//     p0 = S x ; h = S p0                      (S = D^-1/2 A D^-1/2, gather passes)
//     [t1|r1] = h @ [Wl1|Wr1]                  (tiled GEMM)
//     h1 = selu(mean_agg(t1) + r1 + b1)        (gather pass w/ fused epilogue)
//     [t2|r2] = h1 @ [Wl2|Wr2] (+b2 on r2)     (tiled GEMM, 40+40 cols)
//     out = softmax(mean_agg(t2) + r2)         (40-wide gather pass w/ fused softmax)
//   Prop passes use wave-uniform scalar index loads (no shfl/LDS) + 4-wide unroll.

#define RFL(x) __builtin_amdgcn_readfirstlane(x)

// ---------------- CSR build ----------------

__global__ void zero_int_kernel(int* __restrict__ p, int n) {
    int i = blockIdx.x * blockDim.x + threadIdx.x;
    if (i < n) p[i] = 0;
}

__global__ void deg_count_kernel(const int* __restrict__ dst, int* __restrict__ deg, int e) {
    int i = blockIdx.x * blockDim.x + threadIdx.x;
    if (i < e) atomicAdd(&deg[dst[i]], 1);
}

__global__ __launch_bounds__(1024) void scan1_kernel(const int* __restrict__ deg,
                                                     int* __restrict__ incl,
                                                     int* __restrict__ bsum, int n) {
    __shared__ int tmp[1024];
    int t = threadIdx.x;
    int gi = blockIdx.x * 1024 + t;
    int v = (gi < n) ? deg[gi] : 0;
    tmp[t] = v;
    __syncthreads();
    for (int off = 1; off < 1024; off <<= 1) {
        int u = (t >= off) ? tmp[t - off] : 0;
        __syncthreads();
        tmp[t] += u;
        __syncthreads();
    }
    if (gi < n) incl[gi] = tmp[t];
    if (t == 1023) bsum[blockIdx.x] = tmp[1023];
}

__global__ __launch_bounds__(1024) void scan2_kernel(int* __restrict__ bsum, int nb) {
    __shared__ int tmp[1024];
    int t = threadIdx.x;
    int v = (t < nb) ? bsum[t] : 0;
    tmp[t] = v;
    __syncthreads();
    for (int off = 1; off < 1024; off <<= 1) {
        int u = (t >= off) ? tmp[t - off] : 0;
        __syncthreads();
        tmp[t] += u;
        __syncthreads();
    }
    if (t < nb) bsum[t] = tmp[t] - v;   // exclusive
}

__global__ void scan3_kernel(const int* __restrict__ deg, int* __restrict__ row_ptr,
                             const int* __restrict__ bsum, int* __restrict__ cursor,
                             float* __restrict__ dis, float* __restrict__ cnt_inv,
                             int n, int e) {
    int i = blockIdx.x * blockDim.x + threadIdx.x;
    if (i >= n) return;
    int d = deg[i];
    int ex = row_ptr[i] - d + bsum[i >> 10];
    row_ptr[i] = ex;
    cursor[i] = ex;
    float fd = (float)d;
    dis[i] = (d > 0) ? rsqrtf(fd) : 0.0f;
    cnt_inv[i] = 1.0f / fmaxf(fd, 1.0f);
    if (i == 0) row_ptr[n] = e;
}

__global__ void csr_fill_kernel(const int* __restrict__ src, const int* __restrict__ dst,
                                int* __restrict__ cursor, int* __restrict__ csr, int e) {
    int i = blockIdx.x * blockDim.x + threadIdx.x;
    if (i < e) {
        int p = atomicAdd(&cursor[dst[i]], 1);
        csr[p] = src[i];
    }
}

// ---------------- propagation (gather, wave per node) ----------------
// FW: feature width of `in` rows. USE_W: weight = dis[src]. EPI: 0 plain scale,
// 1 = selu(acc*sc + r + b), 2 = softmax(acc*sc + r) over 40 cols.
template <int FW, bool USE_W, int EPI>
__global__ __launch_bounds__(256) void prop_kernel(const float* __restrict__ in,
                                                   float* __restrict__ out,
                                                   const int* __restrict__ row_ptr,
                                                   const int* __restrict__ csr_src,
                                                   const float* __restrict__ dis,
                                                   const float* __restrict__ nscale,
                                                   const float* __restrict__ r_add,
                                                   const float* __restrict__ bias,
                                                   int n) {
    int lane = threadIdx.x & 63;
    int node = RFL(blockIdx.x * 4 + (threadIdx.x >> 6));   // wave-uniform SGPR
    if (node >= n) return;
    int beg = row_ptr[node];
    int end = row_ptr[node + 1];
    float acc = 0.0f;
    int j = beg;
    // 4 independent gathers in flight; indices/weights are wave-uniform scalar loads
    for (; j + 4 <= end; j += 4) {
        int s0 = csr_src[j + 0];
        int s1 = csr_src[j + 1];
        int s2 = csr_src[j + 2];
        int s3 = csr_src[j + 3];
        float v0 = in[(size_t)s0 * FW + lane];
        float v1 = in[(size_t)s1 * FW + lane];
        float v2 = in[(size_t)s2 * FW + lane];
        float v3 = in[(size_t)s3 * FW + lane];
        if (USE_W) {
            acc += dis[s0] * v0;
            acc += dis[s1] * v1;
            acc += dis[s2] * v2;
            acc += dis[s3] * v3;
        } else {
            acc += v0; acc += v1; acc += v2; acc += v3;
        }
    }
    for (; j < end; ++j) {
        int s = csr_src[j];
        float v = in[(size_t)s * FW + lane];
        acc += USE_W ? dis[s] * v : v;
    }
    float sc = nscale[node];
    if (EPI == 0) {
        out[(size_t)node * FW + lane] = acc * sc;
    } else if (EPI == 1) {
        float t = acc * sc + r_add[(size_t)node * 64 + lane] + bias[lane];
        const float scale = 1.0507009873554805f;
        const float alpha = 1.6732632423543772f;
        t = scale * (t > 0.0f ? t : alpha * expm1f(t));
        out[(size_t)node * 64 + lane] = t;
    } else {
        float t = acc * sc + ((lane < 40) ? r_add[(size_t)node * 40 + lane] : 0.0f);
        float x = (lane < 40) ? t : -INFINITY;
        float m = x;
        for (int off = 32; off; off >>= 1) m = fmaxf(m, __shfl_xor(m, off));
        float e = (lane < 40) ? __expf(x - m) : 0.0f;
        float s = e;
        for (int off = 32; off; off >>= 1) s += __shfl_xor(s, off);
        if (lane < 40) out[(size_t)node * 40 + lane] = e / s;
    }
}

// ---------------- tiled GEMM: [outL|outR] = in(64) @ [Wl|Wr] ----------------
// Block: 256 threads, 64 nodes. OC total output cols (2*HC), CP cols/thread.
// x staged transposed (b128 reads of 4 nodes), weights staged [k][c].
template <int OC, int CP>
__global__ __launch_bounds__(256) void gemm_kernel(const float* __restrict__ in,
                                                   const float* __restrict__ Wl,
                                                   const float* __restrict__ Wr,
                                                   const float* __restrict__ bias,
                                                   float* __restrict__ outL,
                                                   float* __restrict__ outR,
                                                   int n, int add_bias) {
    constexpr int HC = OC / 2;
    constexpr int TX = OC / CP;          // col groups
    constexpr int TY = 256 / TX;         // node groups
    constexpr int NPT = 64 / TY;         // nodes per thread
    constexpr int XP = 68;               // 64 + 4 pad, keeps 16B alignment for b128
    constexpr int WP = OC + 4;
    __shared__ float sXT[64 * XP];       // [k][node]
    __shared__ float sW[64 * WP];        // [k][c]: c<HC -> Wl, else Wr
    int t = threadIdx.x;
    int blk = blockIdx.x;
    // stage x transposed: coalesced global read, conflict-free LDS write
    for (int i = 0; i < 16; ++i) {
        int idx = i * 256 + t;
        int nd = idx >> 6;
        int k = idx & 63;
        int ng = blk * 64 + nd;
        float v = in[(size_t)(ng < n ? ng : n - 1) * 64 + k];
        sXT[k * XP + nd] = v;
    }
    for (int i = t; i < 64 * HC; i += 256) {
        int k = i / HC;
        int c = i % HC;
        sW[k * WP + c] = Wl[i];
        sW[k * WP + HC + c] = Wr[i];
    }
    __syncthreads();
    int tx = t % TX;
    int ty = t / TX;
    float acc[NPT][CP];
#pragma unroll
    for (int i = 0; i < NPT; ++i)
#pragma unroll
        for (int c = 0; c < CP; ++c) acc[i][c] = 0.0f;
#pragma unroll 4
    for (int k = 0; k < 64; ++k) {
        float xv[NPT];
#pragma unroll
        for (int i = 0; i < NPT; ++i) xv[i] = sXT[k * XP + ty * NPT + i];
        float wv[CP];
#pragma unroll
        for (int c = 0; c < CP; ++c) wv[c] = sW[k * WP + tx * CP + c];
#pragma unroll
        for (int i = 0; i < NPT; ++i)
#pragma unroll
            for (int c = 0; c < CP; ++c) acc[i][c] += xv[i] * wv[c];
    }
#pragma unroll
    for (int i = 0; i < NPT; ++i) {
        int ng = blk * 64 + ty * NPT + i;
        if (ng >= n) break;
#pragma unroll
        for (int c = 0; c < CP; ++c) {
            int col = tx * CP + c;
            if (col < HC) {
                outL[(size_t)ng * HC + col] = acc[i][c];
            } else {
                float v = acc[i][c] + (add_bias ? bias[col - HC] : 0.0f);
                outR[(size_t)ng * HC + (col - HC)] = v;
            }
        }
    }
}

// ---------------- launch ----------------

extern "C" void kernel_launch(void* const* d_in, const int* in_sizes, int n_in,
                              void* d_out, int out_size, void* d_ws, size_t ws_size,
                              hipStream_t stream) {
    const float* x   = (const float*)d_in[0];
    const float* Wl1 = (const float*)d_in[1];
    const float* Wr1 = (const float*)d_in[2];
    const float* b1  = (const float*)d_in[3];
    const float* Wl2 = (const float*)d_in[4];
    const float* Wr2 = (const float*)d_in[5];
    const float* b2  = (const float*)d_in[6];
    const int* edge_src = (const int*)d_in[7];
    const int* edge_dst = (const int*)d_in[8];
    float* out = (float*)d_out;

    const int N = in_sizes[0] / 64;
    const int E = in_sizes[7];

    size_t off = 0;
    auto carve = [&](size_t bytes) -> void* {
        void* p = (char*)d_ws + off;
        off = (off + bytes + 255) & ~(size_t)255;
        return p;
    };
    int*   deg     = (int*)carve((size_t)N * 4);
    int*   row_ptr = (int*)carve((size_t)(N + 1) * 4);
    int*   cursor  = (int*)carve((size_t)N * 4);
    int*   bsum    = (int*)carve(1024 * 4);
    float* dis     = (float*)carve((size_t)N * 4);
    float* cnt_inv = (float*)carve((size_t)N * 4);
    int*   csr_src = (int*)carve((size_t)E * 4);
    float* bufA    = (float*)carve((size_t)N * 64 * 4);
    float* bufB    = (float*)carve((size_t)N * 64 * 4);
    float* bufC    = (float*)carve((size_t)N * 64 * 4);
    (void)ws_size;

    const int nb_n256 = (N + 255) / 256;
    const int nb_e256 = (E + 255) / 256;
    const int nb_scan = (N + 1023) / 1024;
    const int nb_node = (N + 3) / 4;     // 4 waves (nodes) per block
    const int nb_gemm = (N + 63) / 64;   // 64 nodes per block

    // CSR build
    zero_int_kernel<<<nb_n256, 256, 0, stream>>>(deg, N);
    deg_count_kernel<<<nb_e256, 256, 0, stream>>>(edge_dst, deg, E);
    scan1_kernel<<<nb_scan, 1024, 0, stream>>>(deg, row_ptr, bsum, N);
    scan2_kernel<<<1, 1024, 0, stream>>>(bsum, nb_scan);
    scan3_kernel<<<nb_n256, 256, 0, stream>>>(deg, row_ptr, bsum, cursor, dis, cnt_inv, N, E);
    csr_fill_kernel<<<nb_e256, 256, 0, stream>>>(edge_src, edge_dst, cursor, csr_src, E);

    // KProp x2: h = S (S x)
    prop_kernel<64, true, 0><<<nb_node, 256, 0, stream>>>(x,    bufA, row_ptr, csr_src, dis, dis, nullptr, nullptr, N);
    prop_kernel<64, true, 0><<<nb_node, 256, 0, stream>>>(bufA, bufB, row_ptr, csr_src, dis, dis, nullptr, nullptr, N);
    // [t1|r1] = h @ [Wl1|Wr1]  (t1 -> bufA, r1 -> bufC)
    gemm_kernel<128, 8><<<nb_gemm, 256, 0, stream>>>(bufB, Wl1, Wr1, nullptr, bufA, bufC, N, 0);
    // h1 = selu(mean_agg(t1) + r1 + b1) -> bufB
    prop_kernel<64, false, 1><<<nb_node, 256, 0, stream>>>(bufA, bufB, row_ptr, csr_src, dis, cnt_inv, bufC, b1, N);
    // [t2|r2+b2] = h1 @ [Wl2|Wr2]  (t2 -> bufA (N x 40), r2 -> bufC (N x 40))
    gemm_kernel<80, 5><<<nb_gemm, 256, 0, stream>>>(bufB, Wl2, Wr2, b2, bufA, bufC, N, 1);
    // out = softmax(mean_agg(t2) + r2)
    prop_kernel<40, false, 2><<<nb_node, 256, 0, stream>>>(bufA, out, row_ptr, csr_src, dis, cnt_inv, bufC, nullptr, N);
}